// Round 4
// baseline (2471.856 us; speedup 1.0000x reference)
//
#include <hip/hip_runtime.h>
#include <hip/hip_bf16.h>

#define N_PTS 400000
#define XN 512
#define YN 512
#define BATCHN 4
#define VOX (XN*YN)            // 262144
#define GRID_NUM (BATCHN*VOX)  // 1048576

static __device__ __forceinline__ float relu_(float x){ return fmaxf(x, 0.0f); }
// valid for v >= 0 with buffer pre-zeroed (non-negative IEEE floats order as ints)
static __device__ __forceinline__ void atomic_max_pos(float* a, float v){
    atomicMax((int*)a, __float_as_int(v));
}
static __device__ __forceinline__ int voxel_id(float px, float py, int b){
    int xg = (int)floorf(px*512.0f);
    int yg = (int)floorf(py*512.0f);
    return b*VOX + yg*XN + xg;
}

// ---------------- zero ws (gridV in convA + seg0/seg1 in convB) each launch
__global__ void kZero(float4* __restrict__ p, int n4){
    int i = blockIdx.x*256 + threadIdx.x;
    const float4 z = make_float4(0.f,0.f,0.f,0.f);
    for (; i < n4; i += gridDim.x*256) p[i] = z;
}

// ---------------- diagnostic: ws too small -> encode ws MiB in output
__global__ void kDiag(float* __restrict__ o, int n, float v){
    int i = blockIdx.x*256 + threadIdx.x;
    for (; i < n; i += gridDim.x*256) o[i] = v;
}

// ---------------- Kernel A: pconv0 -> pconv1 -> concat(dx,dy) -> pconv(v0), scatter seg0
__global__ void kA(const int* __restrict__ bid, const float* __restrict__ pts,
                   const float* __restrict__ w0, const float* __restrict__ b0,
                   const float* __restrict__ s0, const float* __restrict__ t0,
                   const float* __restrict__ w1, const float* __restrict__ b1,
                   const float* __restrict__ s1, const float* __restrict__ t1,
                   const float* __restrict__ wv0, const float* __restrict__ bv0,
                   const float* __restrict__ sv0, const float* __restrict__ tv0,
                   float* __restrict__ obuf, float* __restrict__ seg0)
{
    int i = blockIdx.x*256 + threadIdx.x;
    if (i >= N_PTS) return;
    float p[6];
    #pragma unroll
    for (int r=0;r<6;r++) p[r] = pts[r*N_PTS+i];
    int xg = (int)floorf(p[0]*512.0f);
    int yg = (int)floorf(p[1]*512.0f);
    int gid = bid[i]*VOX + yg*XN + xg;

    float h0[16];
    #pragma unroll
    for (int o=0;o<16;o++){
        float a = b0[o];
        #pragma unroll
        for (int k=0;k<6;k++) a = fmaf(w0[o*6+k], p[k], a);
        h0[o] = relu_(fmaf(a, s0[o], t0[o]));
    }
    float h1[16];
    #pragma unroll
    for (int o=0;o<16;o++){
        float a = b1[o];
        #pragma unroll
        for (int k=0;k<16;k++) a = fmaf(w1[o*16+k], h0[k], a);
        h1[o] = relu_(fmaf(a, s1[o], t1[o]));
    }
    float dx = p[0] - ((float)xg + 0.5f)*(1.0f/512.0f);
    float dy = p[1] - ((float)yg + 0.5f)*(1.0f/512.0f);
    #pragma unroll
    for (int o=0;o<16;o++){
        float a = bv0[o];
        #pragma unroll
        for (int k=0;k<16;k++) a = fmaf(wv0[o*18+k], h1[k], a);
        a = fmaf(wv0[o*18+16], dx, a);
        a = fmaf(wv0[o*18+17], dy, a);
        float v = relu_(fmaf(a, sv0[o], tv0[o]));
        obuf[o*N_PTS+i] = v;
        atomic_max_pos(&seg0[(size_t)gid*16+o], v);
    }
}

// ---------------- Kernel B: concat(o, seg0[gid]) -> pconv(v1), scatter seg1 (in-place obuf)
__global__ void kB(const int* __restrict__ bid, const float* __restrict__ pts,
                   const float* __restrict__ w, const float* __restrict__ bb,
                   const float* __restrict__ ss, const float* __restrict__ tt,
                   float* __restrict__ obuf,
                   const float* __restrict__ segin, float* __restrict__ segout)
{
    int i = blockIdx.x*256 + threadIdx.x;
    if (i >= N_PTS) return;
    int gid = voxel_id(pts[i], pts[N_PTS+i], bid[i]);
    float h[32];
    #pragma unroll
    for (int k=0;k<16;k++) h[k] = obuf[k*N_PTS+i];
    const float4* sp = (const float4*)(segin + (size_t)gid*16);
    #pragma unroll
    for (int q=0;q<4;q++){
        float4 v = sp[q];
        h[16+q*4+0]=v.x; h[16+q*4+1]=v.y; h[16+q*4+2]=v.z; h[16+q*4+3]=v.w;
    }
    float o[16];
    #pragma unroll
    for (int c=0;c<16;c++){
        float a = bb[c];
        #pragma unroll
        for (int k=0;k<32;k++) a = fmaf(w[c*32+k], h[k], a);
        o[c] = relu_(fmaf(a, ss[c], tt[c]));
    }
    #pragma unroll
    for (int c=0;c<16;c++){
        obuf[c*N_PTS+i] = o[c];
        atomic_max_pos(&segout[(size_t)gid*16+c], o[c]);
    }
}

// ---------------- Kernel C: concat(o, seg1[gid]) -> pconv(w2)=point0,
//                  scatter voxel-major gridV[gid][c], pre-project through w3[:, :32]
__global__ void kC(const int* __restrict__ bid, const float* __restrict__ pts,
                   const float* __restrict__ w, const float* __restrict__ bb,
                   const float* __restrict__ ss, const float* __restrict__ tt,
                   const float* __restrict__ w3,
                   float* __restrict__ obuf_and_partial,   // d_out: 16ch obuf in, 20ch partial out
                   const float* __restrict__ segin, float* __restrict__ gridV)
{
    int i = blockIdx.x*256 + threadIdx.x;
    if (i >= N_PTS) return;
    int gid = voxel_id(pts[i], pts[N_PTS+i], bid[i]);
    float h[32];
    #pragma unroll
    for (int k=0;k<16;k++) h[k] = obuf_and_partial[k*N_PTS+i];
    const float4* sp = (const float4*)(segin + (size_t)gid*16);
    #pragma unroll
    for (int q=0;q<4;q++){
        float4 v = sp[q];
        h[16+q*4+0]=v.x; h[16+q*4+1]=v.y; h[16+q*4+2]=v.z; h[16+q*4+3]=v.w;
    }
    float p0v[32];
    #pragma unroll
    for (int c=0;c<32;c++){
        float a = bb[c];
        #pragma unroll
        for (int k=0;k<32;k++) a = fmaf(w[c*32+k], h[k], a);
        float v = relu_(fmaf(a, ss[c], tt[c]));
        p0v[c] = v;
        atomic_max_pos(&gridV[(size_t)gid*32 + c], v);   // 128B contiguous per point
    }
    // partial[k] = w3[k, 0:32] @ point0 ; column i only -> no cross-thread hazard
    #pragma unroll
    for (int k=0;k<20;k++){
        float a = 0.f;
        #pragma unroll
        for (int c=0;c<32;c++) a = fmaf(w3[k*64+c], p0v[c], a);
        obuf_and_partial[(size_t)k*N_PTS+i] = a;
    }
}

// ---------------- transpose voxel-major [GRID_NUM][32] -> NCHW [4][32][512][512]
__global__ __launch_bounds__(256) void kT(const float* __restrict__ src, float* __restrict__ dst)
{
    __shared__ float s[128][33];
    const int tid = threadIdx.x;
    const size_t v0 = (size_t)blockIdx.x * 128;          // 128 voxels per block
    // load: 128 vox x 32 ch = 1024 float4, fully coalesced
    #pragma unroll
    for (int k=0;k<4;k++){
        int idx = tid + k*256;           // float4 index
        int vox = idx >> 3;
        int q   = idx & 7;
        float4 d = ((const float4*)(src + (v0 + vox)*32))[q];
        s[vox][q*4+0]=d.x; s[vox][q*4+1]=d.y; s[vox][q*4+2]=d.z; s[vox][q*4+3]=d.w;
    }
    __syncthreads();
    // write: thread -> channel c = tid>>3, vg = tid&7; per k, 8 lanes of same c write
    // 8 consecutive float4 (one 128B line)
    const int c = tid >> 3, vg = tid & 7;
    const int b = (int)(v0 >> 18);                       // VOX = 2^18
    const size_t rem = v0 & (VOX-1);
    float* outp = dst + (((size_t)(b*32 + c)) << 18) + rem;
    #pragma unroll
    for (int k=0;k<4;k++){
        int vbase = k*32 + vg*4;
        float4 d;
        d.x = s[vbase+0][c]; d.y = s[vbase+1][c];
        d.z = s[vbase+2][c]; d.w = s[vbase+3][c];
        ((float4*)outp)[k*8 + vg] = d;
    }
}

// ---------------- dilated 3x3 conv + BN + ReLU, [4,32,512,512]
// ic-chunked (8 at a time) -> LDS 32.3 KB -> 3 blocks/CU (12 waves) vs old 1 block.
template<int P, bool NHWC>
__global__ __launch_bounds__(256,3) void conv3x3(
    const float* __restrict__ in, float* __restrict__ out,
    const float* __restrict__ W, const float* __restrict__ bb,
    const float* __restrict__ ss, const float* __restrict__ tt)
{
    constexpr int TW = 32, TH = 16;
    constexpr int TIW = TW + 2*P, TIH = TH + 2*P;   // P=2: 36x20; P=1: 34x18
    constexpr int ICC = 8;                          // ic chunk
    __shared__ float sIn[ICC][TIH][TIW];            // 23 KB (P=2)
    __shared__ float sW[ICC][9][32];                // 9.2 KB
    const int tid = threadIdx.x;
    const int x0 = blockIdx.x*TW, y0 = blockIdx.y*TH, bz = blockIdx.z;
    const float* inB = in + (size_t)bz*32*VOX;
    const int tx = tid & 31, ty = tid >> 5;         // pixel (tx, ty) and (tx, ty+8)

    float acc0[32], acc1[32];
    #pragma unroll
    for (int oc=0;oc<32;oc++){ acc0[oc]=0.f; acc1[oc]=0.f; }

    for (int c0 = 0; c0 < 32; c0 += ICC){
        if (c0) __syncthreads();                    // protect previous chunk's reads
        for (int idx = tid; idx < ICC*9*32; idx += 256){
            int oc = idx & 31, tap = (idx>>5)%9, ic = idx/288;
            sW[ic][tap][oc] = W[((size_t)oc*32 + c0 + ic)*9 + tap];
        }
        for (int idx = tid; idx < ICC*TIH*TIW; idx += 256){
            int c = idx % TIW;
            int r = (idx / TIW) % TIH;
            int ic = idx / (TIW*TIH);
            int gy = y0 - P + r, gx = x0 - P + c;
            float v = 0.f;
            if ((unsigned)gy < 512u && (unsigned)gx < 512u)
                v = inB[((size_t)(c0+ic)*512 + gy)*512 + gx];
            sIn[ic][r][c] = v;
        }
        __syncthreads();

        for (int ic=0; ic<ICC; ic++){
            #pragma unroll
            for (int tap=0; tap<9; tap++){
                const int ky = tap/3, kx = tap%3;
                float v0 = sIn[ic][ty +     ky*P][tx + kx*P];
                float v1 = sIn[ic][ty + 8 + ky*P][tx + kx*P];
                const float4* wp = (const float4*)&sW[ic][tap][0];
                #pragma unroll
                for (int q=0;q<8;q++){
                    float4 w4 = wp[q];
                    acc0[q*4+0] = fmaf(v0, w4.x, acc0[q*4+0]);
                    acc0[q*4+1] = fmaf(v0, w4.y, acc0[q*4+1]);
                    acc0[q*4+2] = fmaf(v0, w4.z, acc0[q*4+2]);
                    acc0[q*4+3] = fmaf(v0, w4.w, acc0[q*4+3]);
                    acc1[q*4+0] = fmaf(v1, w4.x, acc1[q*4+0]);
                    acc1[q*4+1] = fmaf(v1, w4.y, acc1[q*4+1]);
                    acc1[q*4+2] = fmaf(v1, w4.z, acc1[q*4+2]);
                    acc1[q*4+3] = fmaf(v1, w4.w, acc1[q*4+3]);
                }
            }
        }
    }

    #pragma unroll
    for (int oc=0; oc<32; oc++){
        float r0 = relu_(fmaf(acc0[oc] + bb[oc], ss[oc], tt[oc]));
        float r1 = relu_(fmaf(acc1[oc] + bb[oc], ss[oc], tt[oc]));
        int gy0 = y0 + ty, gy1 = y0 + ty + 8, gx = x0 + tx;
        if (NHWC){
            out[(((size_t)bz*512 + gy0)*512 + gx)*32 + oc] = r0;
            out[(((size_t)bz*512 + gy1)*512 + gx)*32 + oc] = r1;
        } else {
            out[((size_t)(bz*32+oc)*512 + gy0)*512 + gx] = r0;
            out[((size_t)(bz*32+oc)*512 + gy1)*512 + gx] = r1;
        }
    }
}

// ---------------- bilinear sample (NHWC grid) + add w3[:,32:]@point1 + b3 into d_out
__global__ void kFinal(const int* __restrict__ bid, const float* __restrict__ pts,
                       const float* __restrict__ gridN,
                       const float* __restrict__ w3, const float* __restrict__ b3,
                       float* __restrict__ outp)
{
    int i = blockIdx.x*256 + threadIdx.x;
    if (i >= N_PTS) return;
    float px = pts[i], py = pts[N_PTS+i];
    int b = bid[i];
    float ix = px*512.0f - 1.0f;
    float iy = py*512.0f - 1.0f + (float)(b*512);
    float x0f = floorf(ix), y0f = floorf(iy);
    float wx = ix - x0f, wy = iy - y0f;
    int x0 = (int)x0f, y0 = (int)y0f;

    float p1[32];
    #pragma unroll
    for (int c=0;c<32;c++) p1[c] = 0.f;
    #pragma unroll
    for (int t=0;t<4;t++){
        int yi = y0 + (t>>1);
        int xi = x0 + (t&1);
        if (yi < 0 || yi >= BATCHN*YN || xi < 0 || xi >= XN) continue;
        float wgt = ((t>>1)? wy : 1.0f-wy) * ((t&1)? wx : 1.0f-wx);
        const float4* tp = (const float4*)(gridN + ((size_t)yi*XN + xi)*32);
        #pragma unroll
        for (int q=0;q<8;q++){
            float4 v = tp[q];
            p1[q*4+0] = fmaf(wgt, v.x, p1[q*4+0]);
            p1[q*4+1] = fmaf(wgt, v.y, p1[q*4+1]);
            p1[q*4+2] = fmaf(wgt, v.z, p1[q*4+2]);
            p1[q*4+3] = fmaf(wgt, v.w, p1[q*4+3]);
        }
    }

    #pragma unroll
    for (int k=0;k<20;k++){
        float a = outp[(size_t)k*N_PTS + i] + b3[k];   // partial from kC
        #pragma unroll
        for (int c=0;c<32;c++) a = fmaf(w3[k*64+32+c], p1[c], a);
        outp[(size_t)k*N_PTS + i] = a;
    }
}

extern "C" void kernel_launch(void* const* d_in, const int* in_sizes, int n_in,
                              void* d_out, int out_size, void* d_ws, size_t ws_size,
                              hipStream_t stream)
{
    const int*   bid = (const int*)  d_in[0];
    const float* pts = (const float*)d_in[1];
    const float* w0  = (const float*)d_in[3];
    const float* b0  = (const float*)d_in[4];
    const float* s0  = (const float*)d_in[5];
    const float* t0  = (const float*)d_in[6];
    const float* w1  = (const float*)d_in[7];
    const float* b1  = (const float*)d_in[8];
    const float* s1  = (const float*)d_in[9];
    const float* t1  = (const float*)d_in[10];
    const float* wv0 = (const float*)d_in[11];
    const float* bv0 = (const float*)d_in[12];
    const float* sv0 = (const float*)d_in[13];
    const float* tv0 = (const float*)d_in[14];
    const float* wv1 = (const float*)d_in[15];
    const float* bv1 = (const float*)d_in[16];
    const float* sv1 = (const float*)d_in[17];
    const float* tv1 = (const float*)d_in[18];
    const float* w2  = (const float*)d_in[19];
    const float* b2  = (const float*)d_in[20];
    const float* s2  = (const float*)d_in[21];
    const float* t2  = (const float*)d_in[22];
    const float* w2d = (const float*)d_in[23];
    const float* b2d = (const float*)d_in[24];
    const float* s2d = (const float*)d_in[25];
    const float* t2d = (const float*)d_in[26];
    const float* w3  = (const float*)d_in[27];
    const float* b3  = (const float*)d_in[28];

    const size_t CONV_BYTES = (size_t)BATCHN*32*VOX*4;   // 134,217,728 (128 MiB)
    const size_t NEED = 2*CONV_BYTES;                    // 268,435,456 (256 MiB)
    if (ws_size < NEED){
        // do not fault: report ws budget via output values (absmax ~ ws MiB)
        kDiag<<<512,256,0,stream>>>((float*)d_out, out_size, (float)(ws_size>>20));
        return;
    }

    char* ws = (char*)d_ws;
    float* convA = (float*)(ws);                         // gridV scatter / conv ping
    float* convB = (float*)(ws + CONV_BYTES);            // conv pong
    float* seg0  = convB;                                // 64 MiB, dead before kT writes convB
    float* seg1  = (float*)(ws + CONV_BYTES + (size_t)GRID_NUM*16*4);
    float* gridV = convA;                                // voxel-major [GRID_NUM][32]
    float* obuf  = (float*)d_out;                        // 16ch x N in d_out, then 20ch partial

    // zero gridV (scatter target) + seg0/seg1 (all of convB)
    kZero<<<2048,256,0,stream>>>((float4*)ws, (int)(NEED/16));

    const int nb = (N_PTS + 255)/256;
    kA<<<nb,256,0,stream>>>(bid, pts, w0,b0,s0,t0, w1,b1,s1,t1, wv0,bv0,sv0,tv0,
                            obuf, seg0);
    kB<<<nb,256,0,stream>>>(bid, pts, wv1,bv1,sv1,tv1, obuf, seg0, seg1);
    kC<<<nb,256,0,stream>>>(bid, pts, w2,b2,s2,t2, w3, obuf, seg1, gridV);

    // transpose voxel-major -> NCHW into convB (seg0/seg1 dead now)
    kT<<<GRID_NUM/128,256,0,stream>>>(gridV, convB);

    dim3 cgrid(XN/32, YN/16, BATCHN);
    conv3x3<1,false><<<cgrid,256,0,stream>>>(convB, convA, w2d + 0*9216, b2d + 0,  s2d + 0,  t2d + 0);
    conv3x3<2,false><<<cgrid,256,0,stream>>>(convA, convB, w2d + 1*9216, b2d + 32, s2d + 32, t2d + 32);
    conv3x3<2,false><<<cgrid,256,0,stream>>>(convB, convA, w2d + 2*9216, b2d + 64, s2d + 64, t2d + 64);
    conv3x3<2,true ><<<cgrid,256,0,stream>>>(convA, convB, w2d + 3*9216, b2d + 96, s2d + 96, t2d + 96);

    kFinal<<<nb,256,0,stream>>>(bid, pts, convB, w3, b3, (float*)d_out);
}

// Round 5
// 1646.428 us; speedup vs baseline: 1.5013x; 1.5013x over previous
//
#include <hip/hip_runtime.h>
#include <hip/hip_bf16.h>
#include <hip/hip_fp16.h>

#define N_PTS 400000
#define XN 512
#define YN 512
#define BATCHN 4
#define VOX (XN*YN)            // 262144
#define GRID_NUM (BATCHN*VOX)  // 1048576

typedef unsigned long long u64;

static __device__ __forceinline__ float relu_(float x){ return fmaxf(x, 0.0f); }
static __device__ __forceinline__ int voxel_id(float px, float py, int b){
    int xg = (int)floorf(px*512.0f);
    int yg = (int)floorf(py*512.0f);
    return b*VOX + yg*XN + xg;
}

// ---- packed 4x fp16 scatter-max (values >= 0; fp16 bits of non-neg order as u16)
static __device__ __forceinline__ u64 packh4(const float* v){
    u64 r = 0;
    #pragma unroll
    for (int j=0;j<4;j++){
        unsigned short h = __half_as_ushort(__float2half_rn(v[j]));
        r |= (u64)h << (16*j);
    }
    return r;
}
static __device__ __forceinline__ void unpackh4(u64 w, float* o){
    #pragma unroll
    for (int j=0;j<4;j++)
        o[j] = __half2float(__ushort_as_half((unsigned short)(w >> (16*j))));
}
static __device__ __forceinline__ u64 pkmax4(u64 a, u64 b){
    u64 r = 0;
    #pragma unroll
    for (int j=0;j<4;j++){
        u64 x = (a >> (16*j)) & 0xFFFFull;
        u64 y = (b >> (16*j)) & 0xFFFFull;
        r |= (x > y ? x : y) << (16*j);
    }
    return r;
}
static __device__ __forceinline__ void atomic_max_h4(u64* p, u64 v){
    if (v == 0ull) return;                  // max with 0 = identity (buffer zeroed)
    u64 assumed = 0ull;
    u64 old = atomicCAS(p, assumed, v);     // speculative: most words untouched
    while (old != assumed){
        u64 m = pkmax4(old, v);
        if (m == old) break;                // we lose everywhere -> done
        assumed = old;
        old = atomicCAS(p, assumed, m);
    }
}

// ---------------- zero scratch each launch
__global__ void kZero(float4* __restrict__ p, int n4){
    int i = blockIdx.x*256 + threadIdx.x;
    const float4 z = make_float4(0.f,0.f,0.f,0.f);
    for (; i < n4; i += gridDim.x*256) p[i] = z;
}

// ---------------- diagnostic: ws too small -> encode ws MiB in output
__global__ void kDiag(float* __restrict__ o, int n, float v){
    int i = blockIdx.x*256 + threadIdx.x;
    for (; i < n; i += gridDim.x*256) o[i] = v;
}

// ---------------- Kernel A: pconv0 -> pconv1 -> concat(dx,dy) -> pconv(v0), scatter seg0
__global__ void kA(const int* __restrict__ bid, const float* __restrict__ pts,
                   const float* __restrict__ w0, const float* __restrict__ b0,
                   const float* __restrict__ s0, const float* __restrict__ t0,
                   const float* __restrict__ w1, const float* __restrict__ b1,
                   const float* __restrict__ s1, const float* __restrict__ t1,
                   const float* __restrict__ wv0, const float* __restrict__ bv0,
                   const float* __restrict__ sv0, const float* __restrict__ tv0,
                   float* __restrict__ obuf, u64* __restrict__ seg0)
{
    int i = blockIdx.x*256 + threadIdx.x;
    if (i >= N_PTS) return;
    float p[6];
    #pragma unroll
    for (int r=0;r<6;r++) p[r] = pts[r*N_PTS+i];
    int xg = (int)floorf(p[0]*512.0f);
    int yg = (int)floorf(p[1]*512.0f);
    int gid = bid[i]*VOX + yg*XN + xg;

    float h0[16];
    #pragma unroll
    for (int o=0;o<16;o++){
        float a = b0[o];
        #pragma unroll
        for (int k=0;k<6;k++) a = fmaf(w0[o*6+k], p[k], a);
        h0[o] = relu_(fmaf(a, s0[o], t0[o]));
    }
    float h1[16];
    #pragma unroll
    for (int o=0;o<16;o++){
        float a = b1[o];
        #pragma unroll
        for (int k=0;k<16;k++) a = fmaf(w1[o*16+k], h0[k], a);
        h1[o] = relu_(fmaf(a, s1[o], t1[o]));
    }
    float dx = p[0] - ((float)xg + 0.5f)*(1.0f/512.0f);
    float dy = p[1] - ((float)yg + 0.5f)*(1.0f/512.0f);
    float vv[16];
    #pragma unroll
    for (int o=0;o<16;o++){
        float a = bv0[o];
        #pragma unroll
        for (int k=0;k<16;k++) a = fmaf(wv0[o*18+k], h1[k], a);
        a = fmaf(wv0[o*18+16], dx, a);
        a = fmaf(wv0[o*18+17], dy, a);
        float v = relu_(fmaf(a, sv0[o], tv0[o]));
        vv[o] = v;
        obuf[o*N_PTS+i] = v;
    }
    u64* sp = seg0 + (size_t)gid*4;
    #pragma unroll
    for (int q=0;q<4;q++) atomic_max_h4(sp+q, packh4(&vv[q*4]));
}

// ---------------- Kernel B: concat(o, seg0[gid]) -> pconv(v1), scatter seg1 (in-place obuf)
__global__ void kB(const int* __restrict__ bid, const float* __restrict__ pts,
                   const float* __restrict__ w, const float* __restrict__ bb,
                   const float* __restrict__ ss, const float* __restrict__ tt,
                   float* __restrict__ obuf,
                   const u64* __restrict__ segin, u64* __restrict__ segout)
{
    int i = blockIdx.x*256 + threadIdx.x;
    if (i >= N_PTS) return;
    int gid = voxel_id(pts[i], pts[N_PTS+i], bid[i]);
    float h[32];
    #pragma unroll
    for (int k=0;k<16;k++) h[k] = obuf[k*N_PTS+i];
    const u64* sp = segin + (size_t)gid*4;
    #pragma unroll
    for (int q=0;q<4;q++) unpackh4(sp[q], &h[16+q*4]);

    float o[16];
    #pragma unroll
    for (int c=0;c<16;c++){
        float a = bb[c];
        #pragma unroll
        for (int k=0;k<32;k++) a = fmaf(w[c*32+k], h[k], a);
        o[c] = relu_(fmaf(a, ss[c], tt[c]));
    }
    #pragma unroll
    for (int c=0;c<16;c++) obuf[c*N_PTS+i] = o[c];
    u64* dp = segout + (size_t)gid*4;
    #pragma unroll
    for (int q=0;q<4;q++) atomic_max_h4(dp+q, packh4(&o[q*4]));
}

// ---------------- Kernel C: concat(o, seg1[gid]) -> pconv(w2)=point0,
//                  scatter packed-fp16 gridV[gid][32], pre-project through w3[:, :32]
__global__ void kC(const int* __restrict__ bid, const float* __restrict__ pts,
                   const float* __restrict__ w, const float* __restrict__ bb,
                   const float* __restrict__ ss, const float* __restrict__ tt,
                   const float* __restrict__ w3,
                   float* __restrict__ obuf_and_partial,   // d_out: 16ch obuf in, 20ch partial out
                   const u64* __restrict__ segin, u64* __restrict__ gridV)
{
    int i = blockIdx.x*256 + threadIdx.x;
    if (i >= N_PTS) return;
    int gid = voxel_id(pts[i], pts[N_PTS+i], bid[i]);
    float h[32];
    #pragma unroll
    for (int k=0;k<16;k++) h[k] = obuf_and_partial[k*N_PTS+i];
    const u64* sp = segin + (size_t)gid*4;
    #pragma unroll
    for (int q=0;q<4;q++) unpackh4(sp[q], &h[16+q*4]);

    float p0v[32];
    #pragma unroll
    for (int c=0;c<32;c++){
        float a = bb[c];
        #pragma unroll
        for (int k=0;k<32;k++) a = fmaf(w[c*32+k], h[k], a);
        p0v[c] = relu_(fmaf(a, ss[c], tt[c]));
    }
    u64* gp = gridV + (size_t)gid*8;
    #pragma unroll
    for (int q=0;q<8;q++) atomic_max_h4(gp+q, packh4(&p0v[q*4]));
    // partial[k] = w3[k, 0:32] @ point0 ; column i only -> no cross-thread hazard
    #pragma unroll
    for (int k=0;k<20;k++){
        float a = 0.f;
        #pragma unroll
        for (int c=0;c<32;c++) a = fmaf(w3[k*64+c], p0v[c], a);
        obuf_and_partial[(size_t)k*N_PTS+i] = a;
    }
}

// ---------------- transpose packed-fp16 [GRID_NUM][32] -> NCHW fp32 [4][32][512][512]
__global__ __launch_bounds__(256) void kT(const u64* __restrict__ src, float* __restrict__ dst)
{
    __shared__ unsigned int u[128][17];     // 128 vox x 16 u32 (32 fp16), +1 pad
    const int tid = threadIdx.x;
    const size_t v0 = (size_t)blockIdx.x * 128;
    // load: 128 vox x 64B = 512 uint4, coalesced
    #pragma unroll
    for (int k=0;k<2;k++){
        int idx = tid + k*256;
        int vox = idx >> 2, q = idx & 3;
        uint4 d = ((const uint4*)(src + (v0 + vox)*8))[q];
        u[vox][q*4+0]=d.x; u[vox][q*4+1]=d.y; u[vox][q*4+2]=d.z; u[vox][q*4+3]=d.w;
    }
    __syncthreads();
    const int c = tid >> 3, vg = tid & 7;   // channel, vox subgroup
    const int b = (int)(v0 >> 18);          // VOX = 2^18
    const size_t rem = v0 & (VOX-1);
    float* outp = dst + (((size_t)(b*32 + c)) << 18) + rem;
    const int wsel = c >> 1, hsel = c & 1;
    #pragma unroll
    for (int k=0;k<4;k++){
        int vb = k*32 + vg*4;
        float4 d;
        #pragma unroll
        for (int j=0;j<4;j++){
            unsigned int w = u[vb+j][wsel];
            unsigned short h = hsel ? (unsigned short)(w >> 16) : (unsigned short)(w & 0xFFFF);
            ((float*)&d)[j] = __half2float(__ushort_as_half(h));
        }
        ((float4*)outp)[k*8 + vg] = d;
    }
}

// ---------------- dilated 3x3 conv + BN + ReLU, [4,32,512,512]
template<int P, bool NHWC>
__global__ __launch_bounds__(256,3) void conv3x3(
    const float* __restrict__ in, float* __restrict__ out,
    const float* __restrict__ W, const float* __restrict__ bb,
    const float* __restrict__ ss, const float* __restrict__ tt)
{
    constexpr int TW = 32, TH = 16;
    constexpr int TIW = TW + 2*P, TIH = TH + 2*P;   // P=2: 36x20; P=1: 34x18
    constexpr int ICC = 8;                          // ic chunk
    __shared__ float sIn[ICC][TIH][TIW];            // 23 KB (P=2)
    __shared__ float sW[ICC][9][32];                // 9.2 KB
    const int tid = threadIdx.x;
    const int x0 = blockIdx.x*TW, y0 = blockIdx.y*TH, bz = blockIdx.z;
    const float* inB = in + (size_t)bz*32*VOX;
    const int tx = tid & 31, ty = tid >> 5;         // pixel (tx, ty) and (tx, ty+8)

    float acc0[32], acc1[32];
    #pragma unroll
    for (int oc=0;oc<32;oc++){ acc0[oc]=0.f; acc1[oc]=0.f; }

    for (int c0 = 0; c0 < 32; c0 += ICC){
        if (c0) __syncthreads();                    // protect previous chunk's reads
        for (int idx = tid; idx < ICC*9*32; idx += 256){
            int oc = idx & 31, tap = (idx>>5)%9, ic = idx/288;
            sW[ic][tap][oc] = W[((size_t)oc*32 + c0 + ic)*9 + tap];
        }
        for (int idx = tid; idx < ICC*TIH*TIW; idx += 256){
            int c = idx % TIW;
            int r = (idx / TIW) % TIH;
            int ic = idx / (TIW*TIH);
            int gy = y0 - P + r, gx = x0 - P + c;
            float v = 0.f;
            if ((unsigned)gy < 512u && (unsigned)gx < 512u)
                v = inB[((size_t)(c0+ic)*512 + gy)*512 + gx];
            sIn[ic][r][c] = v;
        }
        __syncthreads();

        for (int ic=0; ic<ICC; ic++){
            #pragma unroll
            for (int tap=0; tap<9; tap++){
                const int ky = tap/3, kx = tap%3;
                float v0 = sIn[ic][ty +     ky*P][tx + kx*P];
                float v1 = sIn[ic][ty + 8 + ky*P][tx + kx*P];
                const float4* wp = (const float4*)&sW[ic][tap][0];
                #pragma unroll
                for (int q=0;q<8;q++){
                    float4 w4 = wp[q];
                    acc0[q*4+0] = fmaf(v0, w4.x, acc0[q*4+0]);
                    acc0[q*4+1] = fmaf(v0, w4.y, acc0[q*4+1]);
                    acc0[q*4+2] = fmaf(v0, w4.z, acc0[q*4+2]);
                    acc0[q*4+3] = fmaf(v0, w4.w, acc0[q*4+3]);
                    acc1[q*4+0] = fmaf(v1, w4.x, acc1[q*4+0]);
                    acc1[q*4+1] = fmaf(v1, w4.y, acc1[q*4+1]);
                    acc1[q*4+2] = fmaf(v1, w4.z, acc1[q*4+2]);
                    acc1[q*4+3] = fmaf(v1, w4.w, acc1[q*4+3]);
                }
            }
        }
    }

    #pragma unroll
    for (int oc=0; oc<32; oc++){
        float r0 = relu_(fmaf(acc0[oc] + bb[oc], ss[oc], tt[oc]));
        float r1 = relu_(fmaf(acc1[oc] + bb[oc], ss[oc], tt[oc]));
        int gy0 = y0 + ty, gy1 = y0 + ty + 8, gx = x0 + tx;
        if (NHWC){
            out[(((size_t)bz*512 + gy0)*512 + gx)*32 + oc] = r0;
            out[(((size_t)bz*512 + gy1)*512 + gx)*32 + oc] = r1;
        } else {
            out[((size_t)(bz*32+oc)*512 + gy0)*512 + gx] = r0;
            out[((size_t)(bz*32+oc)*512 + gy1)*512 + gx] = r1;
        }
    }
}

// ---------------- bilinear sample (NHWC grid) + add w3[:,32:]@point1 + b3 into d_out
__global__ void kFinal(const int* __restrict__ bid, const float* __restrict__ pts,
                       const float* __restrict__ gridN,
                       const float* __restrict__ w3, const float* __restrict__ b3,
                       float* __restrict__ outp)
{
    int i = blockIdx.x*256 + threadIdx.x;
    if (i >= N_PTS) return;
    float px = pts[i], py = pts[N_PTS+i];
    int b = bid[i];
    float ix = px*512.0f - 1.0f;
    float iy = py*512.0f - 1.0f + (float)(b*512);
    float x0f = floorf(ix), y0f = floorf(iy);
    float wx = ix - x0f, wy = iy - y0f;
    int x0 = (int)x0f, y0 = (int)y0f;

    float p1[32];
    #pragma unroll
    for (int c=0;c<32;c++) p1[c] = 0.f;
    #pragma unroll
    for (int t=0;t<4;t++){
        int yi = y0 + (t>>1);
        int xi = x0 + (t&1);
        if (yi < 0 || yi >= BATCHN*YN || xi < 0 || xi >= XN) continue;
        float wgt = ((t>>1)? wy : 1.0f-wy) * ((t&1)? wx : 1.0f-wx);
        const float4* tp = (const float4*)(gridN + ((size_t)yi*XN + xi)*32);
        #pragma unroll
        for (int q=0;q<8;q++){
            float4 v = tp[q];
            p1[q*4+0] = fmaf(wgt, v.x, p1[q*4+0]);
            p1[q*4+1] = fmaf(wgt, v.y, p1[q*4+1]);
            p1[q*4+2] = fmaf(wgt, v.z, p1[q*4+2]);
            p1[q*4+3] = fmaf(wgt, v.w, p1[q*4+3]);
        }
    }

    #pragma unroll
    for (int k=0;k<20;k++){
        float a = outp[(size_t)k*N_PTS + i] + b3[k];   // partial from kC
        #pragma unroll
        for (int c=0;c<32;c++) a = fmaf(w3[k*64+32+c], p1[c], a);
        outp[(size_t)k*N_PTS + i] = a;
    }
}

extern "C" void kernel_launch(void* const* d_in, const int* in_sizes, int n_in,
                              void* d_out, int out_size, void* d_ws, size_t ws_size,
                              hipStream_t stream)
{
    const int*   bid = (const int*)  d_in[0];
    const float* pts = (const float*)d_in[1];
    const float* w0  = (const float*)d_in[3];
    const float* b0  = (const float*)d_in[4];
    const float* s0  = (const float*)d_in[5];
    const float* t0  = (const float*)d_in[6];
    const float* w1  = (const float*)d_in[7];
    const float* b1  = (const float*)d_in[8];
    const float* s1  = (const float*)d_in[9];
    const float* t1  = (const float*)d_in[10];
    const float* wv0 = (const float*)d_in[11];
    const float* bv0 = (const float*)d_in[12];
    const float* sv0 = (const float*)d_in[13];
    const float* tv0 = (const float*)d_in[14];
    const float* wv1 = (const float*)d_in[15];
    const float* bv1 = (const float*)d_in[16];
    const float* sv1 = (const float*)d_in[17];
    const float* tv1 = (const float*)d_in[18];
    const float* w2  = (const float*)d_in[19];
    const float* b2  = (const float*)d_in[20];
    const float* s2  = (const float*)d_in[21];
    const float* t2  = (const float*)d_in[22];
    const float* w2d = (const float*)d_in[23];
    const float* b2d = (const float*)d_in[24];
    const float* s2d = (const float*)d_in[25];
    const float* t2d = (const float*)d_in[26];
    const float* w3  = (const float*)d_in[27];
    const float* b3  = (const float*)d_in[28];

    const size_t CONV_BYTES = (size_t)BATCHN*32*VOX*4;   // 134,217,728 (128 MiB)
    const size_t NEED = 2*CONV_BYTES;                    // 268,435,456 (256 MiB)
    if (ws_size < NEED){
        kDiag<<<512,256,0,stream>>>((float*)d_out, out_size, (float)(ws_size>>20));
        return;
    }

    char* ws = (char*)d_ws;
    float* convA = (float*)(ws);                         // conv ping; first 64MB = gridV (fp16 packed)
    float* convB = (float*)(ws + CONV_BYTES);            // conv pong; first 64MB = seg0+seg1
    u64*   gridV = (u64*)convA;                          // [GRID_NUM][8] u64 = 64 MiB
    u64*   seg0  = (u64*)convB;                          // [GRID_NUM][4] u64 = 32 MiB
    u64*   seg1  = (u64*)(ws + CONV_BYTES + (size_t)GRID_NUM*32);
    float* obuf  = (float*)d_out;                        // 16ch x N in d_out, then 20ch partial

    // zero gridV (64MB) + seg0/seg1 (64MB)
    kZero<<<2048,256,0,stream>>>((float4*)gridV, (int)((size_t)GRID_NUM*64/16));
    kZero<<<2048,256,0,stream>>>((float4*)seg0,  (int)((size_t)GRID_NUM*64/16));

    const int nb = (N_PTS + 255)/256;
    kA<<<nb,256,0,stream>>>(bid, pts, w0,b0,s0,t0, w1,b1,s1,t1, wv0,bv0,sv0,tv0,
                            obuf, seg0);
    kB<<<nb,256,0,stream>>>(bid, pts, wv1,bv1,sv1,tv1, obuf, seg0, seg1);
    kC<<<nb,256,0,stream>>>(bid, pts, w2,b2,s2,t2, w3, obuf, seg1, gridV);

    // transpose packed-fp16 voxel-major -> NCHW fp32 into convB (seg0/seg1 dead now)
    kT<<<GRID_NUM/128,256,0,stream>>>(gridV, convB);

    dim3 cgrid(XN/32, YN/16, BATCHN);
    conv3x3<1,false><<<cgrid,256,0,stream>>>(convB, convA, w2d + 0*9216, b2d + 0,  s2d + 0,  t2d + 0);
    conv3x3<2,false><<<cgrid,256,0,stream>>>(convA, convB, w2d + 1*9216, b2d + 32, s2d + 32, t2d + 32);
    conv3x3<2,false><<<cgrid,256,0,stream>>>(convB, convA, w2d + 2*9216, b2d + 64, s2d + 64, t2d + 64);
    conv3x3<2,true ><<<cgrid,256,0,stream>>>(convA, convB, w2d + 3*9216, b2d + 96, s2d + 96, t2d + 96);

    kFinal<<<nb,256,0,stream>>>(bid, pts, convB, w3, b3, (float*)d_out);
}

// Round 6
// 633.428 us; speedup vs baseline: 3.9023x; 2.5992x over previous
//
#include <hip/hip_runtime.h>
#include <hip/hip_bf16.h>
#include <hip/hip_fp16.h>

#define N_PTS 400000
#define XN 512
#define YN 512
#define BATCHN 4
#define VOX (XN*YN)            // 262144
#define GRID_NUM (BATCHN*VOX)  // 1048576

typedef unsigned long long u64;
typedef __attribute__((ext_vector_type(8))) _Float16 f16x8;
typedef __attribute__((ext_vector_type(4))) float f32x4;

static __device__ __forceinline__ float relu_(float x){ return fmaxf(x, 0.0f); }
static __device__ __forceinline__ int voxel_id(float px, float py, int b){
    int xg = (int)floorf(px*512.0f);
    int yg = (int)floorf(py*512.0f);
    return b*VOX + yg*XN + xg;
}

// ---- packed 4x fp16 scatter-max (values >= 0; fp16 bits of non-neg order as u16)
static __device__ __forceinline__ u64 packh4(const float* v){
    u64 r = 0;
    #pragma unroll
    for (int j=0;j<4;j++){
        unsigned short h = __half_as_ushort(__float2half_rn(v[j]));
        r |= (u64)h << (16*j);
    }
    return r;
}
static __device__ __forceinline__ void unpackh4(u64 w, float* o){
    #pragma unroll
    for (int j=0;j<4;j++)
        o[j] = __half2float(__ushort_as_half((unsigned short)(w >> (16*j))));
}
static __device__ __forceinline__ u64 pkmax4(u64 a, u64 b){
    u64 r = 0;
    #pragma unroll
    for (int j=0;j<4;j++){
        u64 x = (a >> (16*j)) & 0xFFFFull;
        u64 y = (b >> (16*j)) & 0xFFFFull;
        r |= (x > y ? x : y) << (16*j);
    }
    return r;
}
static __device__ __forceinline__ void atomic_max_h4(u64* p, u64 v){
    if (v == 0ull) return;                  // max with 0 = identity (buffer zeroed)
    u64 assumed = 0ull;
    u64 old = atomicCAS(p, assumed, v);     // speculative: most words untouched
    while (old != assumed){
        u64 m = pkmax4(old, v);
        if (m == old) break;                // we lose everywhere -> done
        assumed = old;
        old = atomicCAS(p, assumed, m);
    }
}

// ---------------- zero scratch each launch
__global__ void kZero(float4* __restrict__ p, int n4){
    int i = blockIdx.x*256 + threadIdx.x;
    const float4 z = make_float4(0.f,0.f,0.f,0.f);
    for (; i < n4; i += gridDim.x*256) p[i] = z;
}

// ---------------- diagnostic: ws too small -> encode ws MiB in output
__global__ void kDiag(float* __restrict__ o, int n, float v){
    int i = blockIdx.x*256 + threadIdx.x;
    for (; i < n; i += gridDim.x*256) o[i] = v;
}

// ---------------- Kernel A: pconv0 -> pconv1 -> concat(dx,dy) -> pconv(v0), scatter seg0
__global__ void kA(const int* __restrict__ bid, const float* __restrict__ pts,
                   const float* __restrict__ w0, const float* __restrict__ b0,
                   const float* __restrict__ s0, const float* __restrict__ t0,
                   const float* __restrict__ w1, const float* __restrict__ b1,
                   const float* __restrict__ s1, const float* __restrict__ t1,
                   const float* __restrict__ wv0, const float* __restrict__ bv0,
                   const float* __restrict__ sv0, const float* __restrict__ tv0,
                   float* __restrict__ obuf, u64* __restrict__ seg0)
{
    int i = blockIdx.x*256 + threadIdx.x;
    if (i >= N_PTS) return;
    float p[6];
    #pragma unroll
    for (int r=0;r<6;r++) p[r] = pts[r*N_PTS+i];
    int xg = (int)floorf(p[0]*512.0f);
    int yg = (int)floorf(p[1]*512.0f);
    int gid = bid[i]*VOX + yg*XN + xg;

    float h0[16];
    #pragma unroll
    for (int o=0;o<16;o++){
        float a = b0[o];
        #pragma unroll
        for (int k=0;k<6;k++) a = fmaf(w0[o*6+k], p[k], a);
        h0[o] = relu_(fmaf(a, s0[o], t0[o]));
    }
    float h1[16];
    #pragma unroll
    for (int o=0;o<16;o++){
        float a = b1[o];
        #pragma unroll
        for (int k=0;k<16;k++) a = fmaf(w1[o*16+k], h0[k], a);
        h1[o] = relu_(fmaf(a, s1[o], t1[o]));
    }
    float dx = p[0] - ((float)xg + 0.5f)*(1.0f/512.0f);
    float dy = p[1] - ((float)yg + 0.5f)*(1.0f/512.0f);
    float vv[16];
    #pragma unroll
    for (int o=0;o<16;o++){
        float a = bv0[o];
        #pragma unroll
        for (int k=0;k<16;k++) a = fmaf(wv0[o*18+k], h1[k], a);
        a = fmaf(wv0[o*18+16], dx, a);
        a = fmaf(wv0[o*18+17], dy, a);
        float v = relu_(fmaf(a, sv0[o], tv0[o]));
        vv[o] = v;
        obuf[o*N_PTS+i] = v;
    }
    u64* sp = seg0 + (size_t)gid*4;
    #pragma unroll
    for (int q=0;q<4;q++) atomic_max_h4(sp+q, packh4(&vv[q*4]));
}

// ---------------- Kernel B: concat(o, seg0[gid]) -> pconv(v1), scatter seg1 (in-place obuf)
__global__ void kB(const int* __restrict__ bid, const float* __restrict__ pts,
                   const float* __restrict__ w, const float* __restrict__ bb,
                   const float* __restrict__ ss, const float* __restrict__ tt,
                   float* __restrict__ obuf,
                   const u64* __restrict__ segin, u64* __restrict__ segout)
{
    int i = blockIdx.x*256 + threadIdx.x;
    if (i >= N_PTS) return;
    int gid = voxel_id(pts[i], pts[N_PTS+i], bid[i]);
    float h[32];
    #pragma unroll
    for (int k=0;k<16;k++) h[k] = obuf[k*N_PTS+i];
    const u64* sp = segin + (size_t)gid*4;
    #pragma unroll
    for (int q=0;q<4;q++) unpackh4(sp[q], &h[16+q*4]);

    float o[16];
    #pragma unroll
    for (int c=0;c<16;c++){
        float a = bb[c];
        #pragma unroll
        for (int k=0;k<32;k++) a = fmaf(w[c*32+k], h[k], a);
        o[c] = relu_(fmaf(a, ss[c], tt[c]));
    }
    #pragma unroll
    for (int c=0;c<16;c++) obuf[c*N_PTS+i] = o[c];
    u64* dp = segout + (size_t)gid*4;
    #pragma unroll
    for (int q=0;q<4;q++) atomic_max_h4(dp+q, packh4(&o[q*4]));
}

// ---------------- Kernel C: concat(o, seg1[gid]) -> pconv(w2)=point0,
//                  scatter packed-fp16 gridV (NHWC fp16!), pre-project w3[:, :32]
__global__ void kC(const int* __restrict__ bid, const float* __restrict__ pts,
                   const float* __restrict__ w, const float* __restrict__ bb,
                   const float* __restrict__ ss, const float* __restrict__ tt,
                   const float* __restrict__ w3,
                   float* __restrict__ obuf_and_partial,   // d_out: 16ch obuf in, 20ch partial out
                   const u64* __restrict__ segin, u64* __restrict__ gridV)
{
    int i = blockIdx.x*256 + threadIdx.x;
    if (i >= N_PTS) return;
    int gid = voxel_id(pts[i], pts[N_PTS+i], bid[i]);
    float h[32];
    #pragma unroll
    for (int k=0;k<16;k++) h[k] = obuf_and_partial[k*N_PTS+i];
    const u64* sp = segin + (size_t)gid*4;
    #pragma unroll
    for (int q=0;q<4;q++) unpackh4(sp[q], &h[16+q*4]);

    float p0v[32];
    #pragma unroll
    for (int c=0;c<32;c++){
        float a = bb[c];
        #pragma unroll
        for (int k=0;k<32;k++) a = fmaf(w[c*32+k], h[k], a);
        p0v[c] = relu_(fmaf(a, ss[c], tt[c]));
    }
    u64* gp = gridV + (size_t)gid*8;
    #pragma unroll
    for (int q=0;q<8;q++) atomic_max_h4(gp+q, packh4(&p0v[q*4]));
    #pragma unroll
    for (int k=0;k<20;k++){
        float a = 0.f;
        #pragma unroll
        for (int c=0;c<32;c++) a = fmaf(w3[k*64+c], p0v[c], a);
        obuf_and_partial[(size_t)k*N_PTS+i] = a;
    }
}

// ---------------- dilated 3x3 conv + BN + ReLU via MFMA implicit GEMM
// in/out: NHWC fp16 [4][512][512][32]. D[px,oc] = sum_tap A_tap[px,ic] x W_tap[ic,oc]
template<int P>
__global__ __launch_bounds__(256,2) void convM(
    const _Float16* __restrict__ in, _Float16* __restrict__ out,
    const float* __restrict__ W32, const float* __restrict__ bb,
    const float* __restrict__ ss, const float* __restrict__ tt)
{
    constexpr int TW = 32, TH = 16;
    constexpr int TIW = TW + 2*P, TIH = TH + 2*P;
    // A tile: [TIH rows][TIW px], px stride 5 uint4 (80B: 64B data + 16B pad)
    __shared__ uint4 sA[TIH*TIW*5];
    // W fragments: [tap][ntile][lane] -> 8 halves, linear per lane
    __shared__ uint4 sW4[9*2*64];
    const int tid = threadIdx.x;
    const int lane = tid & 63, wv = tid >> 6;
    const int x0 = blockIdx.x*TW, y0 = blockIdx.y*TH, bz = blockIdx.z;
    const _Float16* inB = in + (size_t)bz*VOX*32;

    // stage weight fragments: lane l, elem j -> W[ic=(l>>4)*8+j][oc=nt*16+(l&15)], tap t
    {
        _Float16* sWh = (_Float16*)sW4;
        for (int idx = tid; idx < 9216; idx += 256){
            int j = idx & 7, ln = (idx>>3) & 63, rest = idx >> 9;  // rest = t*2+nt
            int t = rest >> 1, nt = rest & 1;
            int ic = (ln>>4)*8 + j, oc = nt*16 + (ln&15);
            sWh[idx] = (_Float16)W32[((size_t)oc*32 + ic)*9 + t];
        }
    }
    // stage input tile (halo, zero-padded), 16B units
    for (int u = tid; u < TIH*TIW*4; u += 256){
        int g = u & 3;
        int pxr = u >> 2;
        int px = pxr % TIW, r = pxr / TIW;
        int gy = y0 - P + r, gx = x0 - P + px;
        uint4 v = make_uint4(0,0,0,0);
        if ((unsigned)gy < 512u && (unsigned)gx < 512u)
            v = *(const uint4*)(inB + (((size_t)gy*512 + gx)*32 + g*8));
        sA[(r*TIW + px)*5 + g] = v;
    }
    __syncthreads();

    const f16x8* pA = (const f16x8*)sA;
    const f16x8* pW = (const f16x8*)sW4;
    const int aoff = (lane&15)*5 + (lane>>4);
    const int rowbase = wv*4;

    f32x4 acc[8][2];
    #pragma unroll
    for (int m=0;m<8;m++){ acc[m][0]=(f32x4)0.f; acc[m][1]=(f32x4)0.f; }

    #pragma unroll
    for (int t=0;t<9;t++){
        const int ky = t/3, kx = t%3;
        f16x8 b0 = pW[(t*2+0)*64 + lane];
        f16x8 b1 = pW[(t*2+1)*64 + lane];
        #pragma unroll
        for (int m=0;m<8;m++){
            int r = rowbase + (m>>1) + ky*P;
            int pxb = (m&1)*16 + kx*P;
            f16x8 a = pA[(r*TIW + pxb)*5 + aoff];
            acc[m][0] = __builtin_amdgcn_mfma_f32_16x16x32_f16(a, b0, acc[m][0], 0,0,0);
            acc[m][1] = __builtin_amdgcn_mfma_f32_16x16x32_f16(a, b1, acc[m][1], 0,0,0);
        }
    }

    // epilogue: C/D lane map: col(oc16)=lane&15, row(px16)=(lane>>4)*4+reg
    float bn[2], sn[2], tn[2];
    #pragma unroll
    for (int n=0;n<2;n++){
        int oc = n*16 + (lane&15);
        bn[n] = bb[oc]; sn[n] = ss[oc]; tn[n] = tt[oc];
    }
    _Float16* outB = out + (size_t)bz*VOX*32;
    #pragma unroll
    for (int m=0;m<8;m++){
        int y = y0 + rowbase + (m>>1);
        int xb = x0 + (m&1)*16 + (lane>>4)*4;
        #pragma unroll
        for (int n=0;n<2;n++){
            int oc = n*16 + (lane&15);
            #pragma unroll
            for (int r=0;r<4;r++){
                float v = relu_(fmaf(acc[m][n][r] + bn[n], sn[n], tn[n]));
                outB[(((size_t)y*512) + (xb + r))*32 + oc] = (_Float16)v;
            }
        }
    }
}

// ---------------- bilinear sample (NHWC fp16 grid) + add w3[:,32:]@point1 + b3
__global__ void kFinal(const int* __restrict__ bid, const float* __restrict__ pts,
                       const _Float16* __restrict__ gridH,
                       const float* __restrict__ w3, const float* __restrict__ b3,
                       float* __restrict__ outp)
{
    int i = blockIdx.x*256 + threadIdx.x;
    if (i >= N_PTS) return;
    float px = pts[i], py = pts[N_PTS+i];
    int b = bid[i];
    float ix = px*512.0f - 1.0f;
    float iy = py*512.0f - 1.0f + (float)(b*512);
    float x0f = floorf(ix), y0f = floorf(iy);
    float wx = ix - x0f, wy = iy - y0f;
    int x0 = (int)x0f, y0 = (int)y0f;

    float p1[32];
    #pragma unroll
    for (int c=0;c<32;c++) p1[c] = 0.f;
    #pragma unroll
    for (int t=0;t<4;t++){
        int yi = y0 + (t>>1);
        int xi = x0 + (t&1);
        if (yi < 0 || yi >= BATCHN*YN || xi < 0 || xi >= XN) continue;
        float wgt = ((t>>1)? wy : 1.0f-wy) * ((t&1)? wx : 1.0f-wx);
        const uint4* tp = (const uint4*)(gridH + ((size_t)yi*XN + xi)*32);
        #pragma unroll
        for (int q=0;q<4;q++){
            uint4 v = tp[q];
            const unsigned int* vu = (const unsigned int*)&v;
            #pragma unroll
            for (int e=0;e<4;e++){
                float lo = __half2float(__ushort_as_half((unsigned short)(vu[e] & 0xFFFF)));
                float hi = __half2float(__ushort_as_half((unsigned short)(vu[e] >> 16)));
                p1[q*8 + e*2 + 0] = fmaf(wgt, lo, p1[q*8 + e*2 + 0]);
                p1[q*8 + e*2 + 1] = fmaf(wgt, hi, p1[q*8 + e*2 + 1]);
            }
        }
    }

    #pragma unroll
    for (int k=0;k<20;k++){
        float a = outp[(size_t)k*N_PTS + i] + b3[k];   // partial from kC
        #pragma unroll
        for (int c=0;c<32;c++) a = fmaf(w3[k*64+32+c], p1[c], a);
        outp[(size_t)k*N_PTS + i] = a;
    }
}

extern "C" void kernel_launch(void* const* d_in, const int* in_sizes, int n_in,
                              void* d_out, int out_size, void* d_ws, size_t ws_size,
                              hipStream_t stream)
{
    const int*   bid = (const int*)  d_in[0];
    const float* pts = (const float*)d_in[1];
    const float* w0  = (const float*)d_in[3];
    const float* b0  = (const float*)d_in[4];
    const float* s0  = (const float*)d_in[5];
    const float* t0  = (const float*)d_in[6];
    const float* w1  = (const float*)d_in[7];
    const float* b1  = (const float*)d_in[8];
    const float* s1  = (const float*)d_in[9];
    const float* t1  = (const float*)d_in[10];
    const float* wv0 = (const float*)d_in[11];
    const float* bv0 = (const float*)d_in[12];
    const float* sv0 = (const float*)d_in[13];
    const float* tv0 = (const float*)d_in[14];
    const float* wv1 = (const float*)d_in[15];
    const float* bv1 = (const float*)d_in[16];
    const float* sv1 = (const float*)d_in[17];
    const float* tv1 = (const float*)d_in[18];
    const float* w2  = (const float*)d_in[19];
    const float* b2  = (const float*)d_in[20];
    const float* s2  = (const float*)d_in[21];
    const float* t2  = (const float*)d_in[22];
    const float* w2d = (const float*)d_in[23];
    const float* b2d = (const float*)d_in[24];
    const float* s2d = (const float*)d_in[25];
    const float* t2d = (const float*)d_in[26];
    const float* w3  = (const float*)d_in[27];
    const float* b3  = (const float*)d_in[28];

    const size_t MB = 1024*1024;
    const size_t NEED = 192*MB;
    if (ws_size < NEED){
        kDiag<<<512,256,0,stream>>>((float*)d_out, out_size, (float)(ws_size>>20));
        return;
    }

    char* ws = (char*)d_ws;
    u64*      gridV = (u64*)ws;                          // [GRID_NUM][8] u64 = 64 MiB, == NHWC fp16
    u64*      seg0  = (u64*)(ws + 64*MB);                // 32 MiB
    u64*      seg1  = (u64*)(ws + 96*MB);                // 32 MiB
    _Float16* pong  = (_Float16*)(ws + 128*MB);          // 64 MiB NHWC fp16
    _Float16* ping  = (_Float16*)ws;                     // aliases gridV
    float*    obuf  = (float*)d_out;

    // zero gridV + seg0 + seg1 (contiguous 128 MiB)
    kZero<<<2048,256,0,stream>>>((float4*)ws, (int)(128*MB/16));

    const int nb = (N_PTS + 255)/256;
    kA<<<nb,256,0,stream>>>(bid, pts, w0,b0,s0,t0, w1,b1,s1,t1, wv0,bv0,sv0,tv0,
                            obuf, seg0);
    kB<<<nb,256,0,stream>>>(bid, pts, wv1,bv1,sv1,tv1, obuf, seg0, seg1);
    kC<<<nb,256,0,stream>>>(bid, pts, w2,b2,s2,t2, w3, obuf, seg1, gridV);

    dim3 cgrid(XN/32, YN/16, BATCHN);
    convM<1><<<cgrid,256,0,stream>>>(ping, pong, w2d + 0*9216, b2d + 0,  s2d + 0,  t2d + 0);
    convM<2><<<cgrid,256,0,stream>>>(pong, ping, w2d + 1*9216, b2d + 32, s2d + 32, t2d + 32);
    convM<2><<<cgrid,256,0,stream>>>(ping, pong, w2d + 2*9216, b2d + 64, s2d + 64, t2d + 64);
    convM<2><<<cgrid,256,0,stream>>>(pong, ping, w2d + 3*9216, b2d + 96, s2d + 96, t2d + 96);

    kFinal<<<nb,256,0,stream>>>(bid, pts, ping, w3, b3, (float*)d_out);
}

// Round 7
// 423.385 us; speedup vs baseline: 5.8383x; 1.4961x over previous
//
#include <hip/hip_runtime.h>
#include <hip/hip_bf16.h>
#include <hip/hip_fp16.h>

#define N_PTS 400000
#define XN 512
#define YN 512
#define BATCHN 4
#define VOX (XN*YN)            // 262144
#define GRID_NUM (BATCHN*VOX)  // 1048576

typedef unsigned long long u64;
typedef __attribute__((ext_vector_type(8))) _Float16 f16x8;
typedef __attribute__((ext_vector_type(4))) float f32x4;

static __device__ __forceinline__ float relu_(float x){ return fmaxf(x, 0.0f); }
static __device__ __forceinline__ int voxel_id(float px, float py, int b){
    int xg = (int)floorf(px*512.0f);
    int yg = (int)floorf(py*512.0f);
    return b*VOX + yg*XN + xg;
}

// ---- packed 4x fp16 helpers (values >= 0; fp16 bits of non-neg order as u16)
static __device__ __forceinline__ u64 packh4(const float* v){
    u64 r = 0;
    #pragma unroll
    for (int j=0;j<4;j++){
        unsigned short h = __half_as_ushort(__float2half_rn(v[j]));
        r |= (u64)h << (16*j);
    }
    return r;
}
static __device__ __forceinline__ void unpackh4(u64 w, float* o){
    #pragma unroll
    for (int j=0;j<4;j++)
        o[j] = __half2float(__ushort_as_half((unsigned short)(w >> (16*j))));
}
static __device__ __forceinline__ u64 pkmax4(u64 a, u64 b){
    u64 r = 0;
    #pragma unroll
    for (int j=0;j<4;j++){
        u64 x = (a >> (16*j)) & 0xFFFFull;
        u64 y = (b >> (16*j)) & 0xFFFFull;
        r |= (x > y ? x : y) << (16*j);
    }
    return r;
}

// ---------------- zero scratch each launch
__global__ void kZero(float4* __restrict__ p, int n4){
    int i = blockIdx.x*256 + threadIdx.x;
    const float4 z = make_float4(0.f,0.f,0.f,0.f);
    for (; i < n4; i += gridDim.x*256) p[i] = z;
}

// ---------------- diagnostic: ws too small -> encode ws MiB in output
__global__ void kDiag(float* __restrict__ o, int n, float v){
    int i = blockIdx.x*256 + threadIdx.x;
    for (; i < n; i += gridDim.x*256) o[i] = v;
}

// ---------------- histogram of voxel ids (+ cache gids)
__global__ void kHist(const int* __restrict__ bid, const float* __restrict__ pts,
                      unsigned* __restrict__ offs, int* __restrict__ gids)
{
    int i = blockIdx.x*256 + threadIdx.x;
    if (i >= N_PTS) return;
    int gid = voxel_id(pts[i], pts[N_PTS+i], bid[i]);
    gids[i] = gid;
    atomicAdd(&offs[gid], 1u);
}

// ---------------- 3-kernel exclusive scan of offs[GRID_NUM]
__global__ void kScan1(unsigned* __restrict__ offs, unsigned* __restrict__ partials)
{
    __shared__ unsigned sa[256], sb[256];
    const int t = threadIdx.x;
    const int g = blockIdx.x*256 + t;
    unsigned v = offs[g];
    sa[t] = v;
    __syncthreads();
    unsigned* src = sa; unsigned* dst = sb;
    #pragma unroll
    for (int d=1; d<256; d<<=1){
        dst[t] = src[t] + ((t>=d) ? src[t-d] : 0u);
        __syncthreads();
        unsigned* tmp = src; src = dst; dst = tmp;
    }
    unsigned incl = src[t];
    offs[g] = incl - v;                    // exclusive within block
    if (t == 255) partials[blockIdx.x] = incl;
}
__global__ void kScan2(unsigned* __restrict__ partials)   // 4096 entries, 1 block
{
    __shared__ unsigned sa[256], sb[256];
    const int t = threadIdx.x;
    unsigned loc[16]; unsigned sum = 0;
    #pragma unroll
    for (int j=0;j<16;j++){ loc[j] = partials[t*16+j]; sum += loc[j]; }
    sa[t] = sum;
    __syncthreads();
    unsigned* src = sa; unsigned* dst = sb;
    #pragma unroll
    for (int d=1; d<256; d<<=1){
        dst[t] = src[t] + ((t>=d) ? src[t-d] : 0u);
        __syncthreads();
        unsigned* tmp = src; src = dst; dst = tmp;
    }
    unsigned run = src[t] - sum;           // exclusive base for this thread
    #pragma unroll
    for (int j=0;j<16;j++){ unsigned c = loc[j]; partials[t*16+j] = run; run += c; }
}
__global__ void kScan3(unsigned* __restrict__ offs, const unsigned* __restrict__ partials)
{
    int g = blockIdx.x*256 + threadIdx.x;
    offs[g] += partials[blockIdx.x];
}

// ---------------- Kernel A: MLPs -> obufA (packed fp16), place index in order[]
__global__ void kA(const int* __restrict__ bid, const float* __restrict__ pts,
                   const int* __restrict__ gids,
                   const float* __restrict__ w0, const float* __restrict__ b0,
                   const float* __restrict__ s0, const float* __restrict__ t0,
                   const float* __restrict__ w1, const float* __restrict__ b1,
                   const float* __restrict__ s1, const float* __restrict__ t1,
                   const float* __restrict__ wv0, const float* __restrict__ bv0,
                   const float* __restrict__ sv0, const float* __restrict__ tv0,
                   u64* __restrict__ obufA,
                   unsigned* __restrict__ offs, unsigned* __restrict__ order)
{
    int i = blockIdx.x*256 + threadIdx.x;
    if (i >= N_PTS) return;
    float p[6];
    #pragma unroll
    for (int r=0;r<6;r++) p[r] = pts[r*N_PTS+i];
    int xg = (int)floorf(p[0]*512.0f);
    int yg = (int)floorf(p[1]*512.0f);

    float h0[16];
    #pragma unroll
    for (int o=0;o<16;o++){
        float a = b0[o];
        #pragma unroll
        for (int k=0;k<6;k++) a = fmaf(w0[o*6+k], p[k], a);
        h0[o] = relu_(fmaf(a, s0[o], t0[o]));
    }
    float h1[16];
    #pragma unroll
    for (int o=0;o<16;o++){
        float a = b1[o];
        #pragma unroll
        for (int k=0;k<16;k++) a = fmaf(w1[o*16+k], h0[k], a);
        h1[o] = relu_(fmaf(a, s1[o], t1[o]));
    }
    float dx = p[0] - ((float)xg + 0.5f)*(1.0f/512.0f);
    float dy = p[1] - ((float)yg + 0.5f)*(1.0f/512.0f);
    float vv[16];
    #pragma unroll
    for (int o=0;o<16;o++){
        float a = bv0[o];
        #pragma unroll
        for (int k=0;k<16;k++) a = fmaf(wv0[o*18+k], h1[k], a);
        a = fmaf(wv0[o*18+16], dx, a);
        a = fmaf(wv0[o*18+17], dy, a);
        vv[o] = relu_(fmaf(a, sv0[o], tv0[o]));
    }
    u64* op = obufA + (size_t)i*4;
    #pragma unroll
    for (int q=0;q<4;q++) op[q] = packh4(&vv[q*4]);

    int gid = gids[i];
    unsigned pos = atomicAdd(&offs[gid], 1u);
    order[pos] = (unsigned)i;
}

// ---------------- per-voxel max over its points: 16ch (4 u64 words)
__global__ void kSegMax(const unsigned* __restrict__ offs, const unsigned* __restrict__ order,
                        const u64* __restrict__ src, u64* __restrict__ dst)
{
    int v = blockIdx.x*256 + threadIdx.x;
    unsigned s = v ? offs[v-1] : 0u;
    unsigned e = offs[v];
    if (e <= s) return;
    u64 m0=0,m1=0,m2=0,m3=0;
    for (unsigned p=s; p<e; ++p){
        const u64* q = src + (size_t)order[p]*4;
        m0 = pkmax4(m0, q[0]); m1 = pkmax4(m1, q[1]);
        m2 = pkmax4(m2, q[2]); m3 = pkmax4(m3, q[3]);
    }
    u64* d = dst + (size_t)v*4;
    d[0]=m0; d[1]=m1; d[2]=m2; d[3]=m3;
}

// ---------------- per-voxel max, 32ch (8 u64), write ALL voxels (zeros if empty) = NHWC fp16 grid
__global__ void kGridMax(const unsigned* __restrict__ offs, const unsigned* __restrict__ order,
                         const u64* __restrict__ src, u64* __restrict__ dst)
{
    int v = blockIdx.x*256 + threadIdx.x;
    unsigned s = v ? offs[v-1] : 0u;
    unsigned e = offs[v];
    u64 m[8];
    #pragma unroll
    for (int q=0;q<8;q++) m[q] = 0ull;
    for (unsigned p=s; p<e; ++p){
        const u64* q = src + (size_t)order[p]*8;
        #pragma unroll
        for (int j=0;j<8;j++) m[j] = pkmax4(m[j], q[j]);
    }
    u64* d = dst + (size_t)v*8;
    #pragma unroll
    for (int q=0;q<8;q++) d[q] = m[q];
}

// ---------------- Kernel B: concat(obufA, seg0[gid]) -> pconv(v1) -> obufB
__global__ void kB(const int* __restrict__ gids,
                   const float* __restrict__ w, const float* __restrict__ bb,
                   const float* __restrict__ ss, const float* __restrict__ tt,
                   const u64* __restrict__ obufA, const u64* __restrict__ seg0,
                   u64* __restrict__ obufB)
{
    int i = blockIdx.x*256 + threadIdx.x;
    if (i >= N_PTS) return;
    int gid = gids[i];
    float h[32];
    const u64* ap = obufA + (size_t)i*4;
    #pragma unroll
    for (int q=0;q<4;q++) unpackh4(ap[q], &h[q*4]);
    const u64* sp = seg0 + (size_t)gid*4;
    #pragma unroll
    for (int q=0;q<4;q++) unpackh4(sp[q], &h[16+q*4]);

    float o[16];
    #pragma unroll
    for (int c=0;c<16;c++){
        float a = bb[c];
        #pragma unroll
        for (int k=0;k<32;k++) a = fmaf(w[c*32+k], h[k], a);
        o[c] = relu_(fmaf(a, ss[c], tt[c]));
    }
    u64* op = obufB + (size_t)i*4;
    #pragma unroll
    for (int q=0;q<4;q++) op[q] = packh4(&o[q*4]);
}

// ---------------- Kernel C: concat(obufB, seg1[gid]) -> pconv(w2)=point0 -> pbuf,
//                  pre-project through w3[:, :32] into d_out
__global__ void kC(const int* __restrict__ gids,
                   const float* __restrict__ w, const float* __restrict__ bb,
                   const float* __restrict__ ss, const float* __restrict__ tt,
                   const float* __restrict__ w3,
                   const u64* __restrict__ obufB, const u64* __restrict__ seg1,
                   u64* __restrict__ pbuf, float* __restrict__ outp)
{
    int i = blockIdx.x*256 + threadIdx.x;
    if (i >= N_PTS) return;
    int gid = gids[i];
    float h[32];
    const u64* ap = obufB + (size_t)i*4;
    #pragma unroll
    for (int q=0;q<4;q++) unpackh4(ap[q], &h[q*4]);
    const u64* sp = seg1 + (size_t)gid*4;
    #pragma unroll
    for (int q=0;q<4;q++) unpackh4(sp[q], &h[16+q*4]);

    float p0v[32];
    #pragma unroll
    for (int c=0;c<32;c++){
        float a = bb[c];
        #pragma unroll
        for (int k=0;k<32;k++) a = fmaf(w[c*32+k], h[k], a);
        p0v[c] = relu_(fmaf(a, ss[c], tt[c]));
    }
    u64* pp = pbuf + (size_t)i*8;
    #pragma unroll
    for (int q=0;q<8;q++) pp[q] = packh4(&p0v[q*4]);
    #pragma unroll
    for (int k=0;k<20;k++){
        float a = 0.f;
        #pragma unroll
        for (int c=0;c<32;c++) a = fmaf(w3[k*64+c], p0v[c], a);
        outp[(size_t)k*N_PTS+i] = a;
    }
}

// ---------------- dilated 3x3 conv + BN + ReLU via MFMA implicit GEMM
// in/out: NHWC fp16 [4][512][512][32]. D[px,oc] = sum_tap A_tap[px,ic] x W_tap[ic,oc]
template<int P>
__global__ __launch_bounds__(256,2) void convM(
    const _Float16* __restrict__ in, _Float16* __restrict__ out,
    const float* __restrict__ W32, const float* __restrict__ bb,
    const float* __restrict__ ss, const float* __restrict__ tt)
{
    constexpr int TW = 32, TH = 16;
    constexpr int TIW = TW + 2*P, TIH = TH + 2*P;
    __shared__ uint4 sA[TIH*TIW*5];
    __shared__ uint4 sW4[9*2*64];
    const int tid = threadIdx.x;
    const int lane = tid & 63, wv = tid >> 6;
    const int x0 = blockIdx.x*TW, y0 = blockIdx.y*TH, bz = blockIdx.z;
    const _Float16* inB = in + (size_t)bz*VOX*32;

    {
        _Float16* sWh = (_Float16*)sW4;
        for (int idx = tid; idx < 9216; idx += 256){
            int j = idx & 7, ln = (idx>>3) & 63, rest = idx >> 9;
            int t = rest >> 1, nt = rest & 1;
            int ic = (ln>>4)*8 + j, oc = nt*16 + (ln&15);
            sWh[idx] = (_Float16)W32[((size_t)oc*32 + ic)*9 + t];
        }
    }
    for (int u = tid; u < TIH*TIW*4; u += 256){
        int g = u & 3;
        int pxr = u >> 2;
        int px = pxr % TIW, r = pxr / TIW;
        int gy = y0 - P + r, gx = x0 - P + px;
        uint4 v = make_uint4(0,0,0,0);
        if ((unsigned)gy < 512u && (unsigned)gx < 512u)
            v = *(const uint4*)(inB + (((size_t)gy*512 + gx)*32 + g*8));
        sA[(r*TIW + px)*5 + g] = v;
    }
    __syncthreads();

    const f16x8* pA = (const f16x8*)sA;
    const f16x8* pW = (const f16x8*)sW4;
    const int aoff = (lane&15)*5 + (lane>>4);
    const int rowbase = wv*4;

    f32x4 acc[8][2];
    #pragma unroll
    for (int m=0;m<8;m++){ acc[m][0]=(f32x4)0.f; acc[m][1]=(f32x4)0.f; }

    #pragma unroll
    for (int t=0;t<9;t++){
        const int ky = t/3, kx = t%3;
        f16x8 b0 = pW[(t*2+0)*64 + lane];
        f16x8 b1 = pW[(t*2+1)*64 + lane];
        #pragma unroll
        for (int m=0;m<8;m++){
            int r = rowbase + (m>>1) + ky*P;
            int pxb = (m&1)*16 + kx*P;
            f16x8 a = pA[(r*TIW + pxb)*5 + aoff];
            acc[m][0] = __builtin_amdgcn_mfma_f32_16x16x32_f16(a, b0, acc[m][0], 0,0,0);
            acc[m][1] = __builtin_amdgcn_mfma_f32_16x16x32_f16(a, b1, acc[m][1], 0,0,0);
        }
    }

    float bn[2], sn[2], tn[2];
    #pragma unroll
    for (int n=0;n<2;n++){
        int oc = n*16 + (lane&15);
        bn[n] = bb[oc]; sn[n] = ss[oc]; tn[n] = tt[oc];
    }
    _Float16* outB = out + (size_t)bz*VOX*32;
    #pragma unroll
    for (int m=0;m<8;m++){
        int y = y0 + rowbase + (m>>1);
        int xb = x0 + (m&1)*16 + (lane>>4)*4;
        #pragma unroll
        for (int n=0;n<2;n++){
            int oc = n*16 + (lane&15);
            #pragma unroll
            for (int r=0;r<4;r++){
                float v = relu_(fmaf(acc[m][n][r] + bn[n], sn[n], tn[n]));
                outB[(((size_t)y*512) + (xb + r))*32 + oc] = (_Float16)v;
            }
        }
    }
}

// ---------------- bilinear sample (NHWC fp16 grid) + add w3[:,32:]@point1 + b3
__global__ void kFinal(const int* __restrict__ bid, const float* __restrict__ pts,
                       const _Float16* __restrict__ gridH,
                       const float* __restrict__ w3, const float* __restrict__ b3,
                       float* __restrict__ outp)
{
    int i = blockIdx.x*256 + threadIdx.x;
    if (i >= N_PTS) return;
    float px = pts[i], py = pts[N_PTS+i];
    int b = bid[i];
    float ix = px*512.0f - 1.0f;
    float iy = py*512.0f - 1.0f + (float)(b*512);
    float x0f = floorf(ix), y0f = floorf(iy);
    float wx = ix - x0f, wy = iy - y0f;
    int x0 = (int)x0f, y0 = (int)y0f;

    float p1[32];
    #pragma unroll
    for (int c=0;c<32;c++) p1[c] = 0.f;
    #pragma unroll
    for (int t=0;t<4;t++){
        int yi = y0 + (t>>1);
        int xi = x0 + (t&1);
        if (yi < 0 || yi >= BATCHN*YN || xi < 0 || xi >= XN) continue;
        float wgt = ((t>>1)? wy : 1.0f-wy) * ((t&1)? wx : 1.0f-wx);
        const uint4* tp = (const uint4*)(gridH + ((size_t)yi*XN + xi)*32);
        #pragma unroll
        for (int q=0;q<4;q++){
            uint4 v = tp[q];
            const unsigned int* vu = (const unsigned int*)&v;
            #pragma unroll
            for (int e=0;e<4;e++){
                float lo = __half2float(__ushort_as_half((unsigned short)(vu[e] & 0xFFFF)));
                float hi = __half2float(__ushort_as_half((unsigned short)(vu[e] >> 16)));
                p1[q*8 + e*2 + 0] = fmaf(wgt, lo, p1[q*8 + e*2 + 0]);
                p1[q*8 + e*2 + 1] = fmaf(wgt, hi, p1[q*8 + e*2 + 1]);
            }
        }
    }

    #pragma unroll
    for (int k=0;k<20;k++){
        float a = outp[(size_t)k*N_PTS + i] + b3[k];
        #pragma unroll
        for (int c=0;c<32;c++) a = fmaf(w3[k*64+32+c], p1[c], a);
        outp[(size_t)k*N_PTS + i] = a;
    }
}

extern "C" void kernel_launch(void* const* d_in, const int* in_sizes, int n_in,
                              void* d_out, int out_size, void* d_ws, size_t ws_size,
                              hipStream_t stream)
{
    const int*   bid = (const int*)  d_in[0];
    const float* pts = (const float*)d_in[1];
    const float* w0  = (const float*)d_in[3];
    const float* b0  = (const float*)d_in[4];
    const float* s0  = (const float*)d_in[5];
    const float* t0  = (const float*)d_in[6];
    const float* w1  = (const float*)d_in[7];
    const float* b1  = (const float*)d_in[8];
    const float* s1  = (const float*)d_in[9];
    const float* t1  = (const float*)d_in[10];
    const float* wv0 = (const float*)d_in[11];
    const float* bv0 = (const float*)d_in[12];
    const float* sv0 = (const float*)d_in[13];
    const float* tv0 = (const float*)d_in[14];
    const float* wv1 = (const float*)d_in[15];
    const float* bv1 = (const float*)d_in[16];
    const float* sv1 = (const float*)d_in[17];
    const float* tv1 = (const float*)d_in[18];
    const float* w2  = (const float*)d_in[19];
    const float* b2  = (const float*)d_in[20];
    const float* s2  = (const float*)d_in[21];
    const float* t2  = (const float*)d_in[22];
    const float* w2d = (const float*)d_in[23];
    const float* b2d = (const float*)d_in[24];
    const float* s2d = (const float*)d_in[25];
    const float* t2d = (const float*)d_in[26];
    const float* w3  = (const float*)d_in[27];
    const float* b3  = (const float*)d_in[28];

    const size_t MB = 1024*1024;
    const size_t NEED = 192*MB;
    if (ws_size < NEED){
        kDiag<<<512,256,0,stream>>>((float*)d_out, out_size, (float)(ws_size>>20));
        return;
    }

    char* ws = (char*)d_ws;
    u64*      gridV    = (u64*)ws;                        // 64 MiB NHWC fp16 (conv ping)
    _Float16* ping     = (_Float16*)ws;
    _Float16* pong     = (_Float16*)(ws + 64*MB);         // 64 MiB (conv pong)
    u64*      seg0     = (u64*)(ws + 64*MB);              // 32 MiB, alias pong (dead before conv0)
    u64*      seg1     = (u64*)(ws + 96*MB);              // 32 MiB, alias pong
    unsigned* offs     = (unsigned*)(ws + 128*MB);        // 4 MiB hist/offsets
    unsigned* partials = (unsigned*)(ws + 132*MB);        // 16 KiB
    unsigned* order    = (unsigned*)(ws + 133*MB);        // 1.6 MiB
    int*      gids     = (int*)(ws + 135*MB);             // 1.6 MiB
    u64*      obufA    = (u64*)(ws + 137*MB);             // 12.8 MiB [pt][16ch fp16]
    u64*      obufB    = (u64*)(ws + 150*MB);             // 12.8 MiB
    u64*      pbuf     = (u64*)(ws + 163*MB);             // 25.6 MiB [pt][32ch fp16]

    // zero the histogram only
    kZero<<<256,256,0,stream>>>((float4*)offs, (int)(GRID_NUM*4/16));

    const int nb = (N_PTS + 255)/256;
    const int nv = GRID_NUM/256;                          // 4096

    kHist <<<nb,256,0,stream>>>(bid, pts, offs, gids);
    kScan1<<<nv,256,0,stream>>>(offs, partials);
    kScan2<<<1,256,0,stream>>>(partials);
    kScan3<<<nv,256,0,stream>>>(offs, partials);

    kA<<<nb,256,0,stream>>>(bid, pts, gids, w0,b0,s0,t0, w1,b1,s1,t1,
                            wv0,bv0,sv0,tv0, obufA, offs, order);
    kSegMax<<<nv,256,0,stream>>>(offs, order, obufA, seg0);
    kB<<<nb,256,0,stream>>>(gids, wv1,bv1,sv1,tv1, obufA, seg0, obufB);
    kSegMax<<<nv,256,0,stream>>>(offs, order, obufB, seg1);
    kC<<<nb,256,0,stream>>>(gids, w2,b2,s2,t2, w3, obufB, seg1, pbuf, (float*)d_out);
    kGridMax<<<nv,256,0,stream>>>(offs, order, pbuf, gridV);

    dim3 cgrid(XN/32, YN/16, BATCHN);
    convM<1><<<cgrid,256,0,stream>>>(ping, pong, w2d + 0*9216, b2d + 0,  s2d + 0,  t2d + 0);
    convM<2><<<cgrid,256,0,stream>>>(pong, ping, w2d + 1*9216, b2d + 32, s2d + 32, t2d + 32);
    convM<2><<<cgrid,256,0,stream>>>(ping, pong, w2d + 2*9216, b2d + 64, s2d + 64, t2d + 64);
    convM<2><<<cgrid,256,0,stream>>>(pong, ping, w2d + 3*9216, b2d + 96, s2d + 96, t2d + 96);

    kFinal<<<nb,256,0,stream>>>(bid, pts, ping, w3, b3, (float*)d_out);
}